// Round 3
// baseline (607.967 us; speedup 1.0000x reference)
//
#include <hip/hip_runtime.h>
#include <hip/hip_bf16.h>

// ---------------------------------------------------------------------------
// GCN forward: 2x GCNConv (CSR gather aggregation) + segment_max + log_softmax
// ---------------------------------------------------------------------------

__global__ __launch_bounds__(256) void count_kernel(const int* __restrict__ dst,
                                                    int* __restrict__ indeg, int E) {
    int e = blockIdx.x * 256 + threadIdx.x;
    if (e < E) atomicAdd(&indeg[dst[e]], 1);
}

__global__ __launch_bounds__(256) void scanA(const int* __restrict__ in,
                                             int* __restrict__ out,
                                             int* __restrict__ bsum, int N) {
    __shared__ int tmp[256];
    int t = threadIdx.x;
    int g = blockIdx.x * 256 + t;
    int v = (g < N) ? in[g] : 0;
    tmp[t] = v;
    __syncthreads();
#pragma unroll
    for (int off = 1; off < 256; off <<= 1) {
        int add = (t >= off) ? tmp[t - off] : 0;
        __syncthreads();
        if (t >= off) tmp[t] += add;
        __syncthreads();
    }
    if (g < N) out[g] = tmp[t] - v;   // exclusive within block
    if (t == 255) bsum[blockIdx.x] = tmp[255];
}

__global__ __launch_bounds__(256) void scanB(int* __restrict__ bsum, int nb) {
    __shared__ int tmp[256];
    int t = threadIdx.x;
    int v = (t < nb) ? bsum[t] : 0;
    tmp[t] = v;
    __syncthreads();
#pragma unroll
    for (int off = 1; off < 256; off <<= 1) {
        int add = (t >= off) ? tmp[t - off] : 0;
        __syncthreads();
        if (t >= off) tmp[t] += add;
        __syncthreads();
    }
    if (t < nb) bsum[t] = tmp[t] - v;  // exclusive
}

__global__ __launch_bounds__(256) void scanC(int* __restrict__ rowstart,
                                             const int* __restrict__ bsum,
                                             int N, int E) {
    int g = blockIdx.x * 256 + threadIdx.x;
    if (g < N) rowstart[g] += bsum[blockIdx.x];
    if (g == 0) rowstart[N] = E;
}

__global__ __launch_bounds__(256) void dinv_kernel(const int* __restrict__ indeg,
                                                   float* __restrict__ dinv, int N) {
    int i = blockIdx.x * 256 + threadIdx.x;
    if (i < N) dinv[i] = rsqrtf((float)(indeg[i] + 1));  // +1 self loop
}

__global__ __launch_bounds__(256) void fill_csr(const int* __restrict__ src,
                                                const int* __restrict__ dst,
                                                const int* __restrict__ rowstart,
                                                int* __restrict__ fill,
                                                int* __restrict__ csr_src, int E) {
    int e = blockIdx.x * 256 + threadIdx.x;
    if (e < E) {
        int d = dst[e];
        int p = rowstart[d] + atomicAdd(&fill[d], 1);
        csr_src[p] = src[e];
    }
}

__global__ __launch_bounds__(256) void gstart_kernel(const int* __restrict__ batch,
                                                     int* __restrict__ gstart,
                                                     int N, int G) {
    int g = blockIdx.x * 256 + threadIdx.x;
    if (g > G) return;
    if (g == G) { gstart[G] = N; return; }
    int lo = 0, hi = N;
    while (lo < hi) {
        int mid = (lo + hi) >> 1;
        if (batch[mid] < g) lo = mid + 1; else hi = mid;
    }
    gstart[g] = lo;
}

// out[row] = (A[row] @ B) * scale[row];  A:[M,K], B:[K,256], out:[M,256]
template <int K>
__global__ __launch_bounds__(256) void gemm_scaled(const float* __restrict__ A,
                                                   const float* __restrict__ B,
                                                   const float* __restrict__ scale,
                                                   float* __restrict__ out, int M) {
    __shared__ __align__(16) float As[32][32];
    __shared__ __align__(16) float Bs[32][256];
    const int tid = threadIdx.x;
    const int tx = tid & 63;   // 64 col groups of 4
    const int ty = tid >> 6;   // 4 row groups of 8
    const int row0 = blockIdx.x * 32;

    float acc[8][4];
#pragma unroll
    for (int r = 0; r < 8; ++r)
#pragma unroll
        for (int c = 0; c < 4; ++c) acc[r][c] = 0.f;

    for (int k0 = 0; k0 < K; k0 += 32) {
#pragma unroll
        for (int i = 0; i < 32; ++i) Bs[i][tid] = B[(k0 + i) * 256 + tid];
        {
            int ar = tid >> 3;         // 0..31
            int ac = (tid & 7) * 4;    // 0..28
            int grow = row0 + ar;
            float4 av = make_float4(0.f, 0.f, 0.f, 0.f);
            if (grow < M) av = *reinterpret_cast<const float4*>(&A[(size_t)grow * K + k0 + ac]);
            *reinterpret_cast<float4*>(&As[ar][ac]) = av;
        }
        __syncthreads();
#pragma unroll
        for (int kk = 0; kk < 32; kk += 4) {
            float4 bv0 = *reinterpret_cast<const float4*>(&Bs[kk + 0][tx * 4]);
            float4 bv1 = *reinterpret_cast<const float4*>(&Bs[kk + 1][tx * 4]);
            float4 bv2 = *reinterpret_cast<const float4*>(&Bs[kk + 2][tx * 4]);
            float4 bv3 = *reinterpret_cast<const float4*>(&Bs[kk + 3][tx * 4]);
#pragma unroll
            for (int r = 0; r < 8; ++r) {
                float4 av = *reinterpret_cast<const float4*>(&As[ty * 8 + r][kk]);
                acc[r][0] += av.x * bv0.x + av.y * bv1.x + av.z * bv2.x + av.w * bv3.x;
                acc[r][1] += av.x * bv0.y + av.y * bv1.y + av.z * bv2.y + av.w * bv3.y;
                acc[r][2] += av.x * bv0.z + av.y * bv1.z + av.z * bv2.z + av.w * bv3.z;
                acc[r][3] += av.x * bv0.w + av.y * bv1.w + av.z * bv2.w + av.w * bv3.w;
            }
        }
        __syncthreads();
    }
#pragma unroll
    for (int r = 0; r < 8; ++r) {
        int grow = row0 + ty * 8 + r;
        if (grow < M) {
            float s = scale[grow];
            float4 v = make_float4(acc[r][0] * s, acc[r][1] * s, acc[r][2] * s, acc[r][3] * s);
            *reinterpret_cast<float4*>(&out[(size_t)grow * 256 + tx * 4]) = v;
        }
    }
}

// out[i] = maybe_relu(dinv[i] * (hs[i] + sum_{e: s->i} hs[s]) + bias)
// 4-way unrolled edge loop: 4 independent accumulators keep 4 row-gathers
// in flight (avg degree ~16; the serial loop was latency-bound otherwise).
__global__ __launch_bounds__(256) void agg_kernel(const float* __restrict__ hs,
                                                  const int* __restrict__ rowstart,
                                                  const int* __restrict__ csr_src,
                                                  const float* __restrict__ dinv,
                                                  const float* __restrict__ bias,
                                                  float* __restrict__ out,
                                                  int do_relu) {
    int i = blockIdx.x;
    int t = threadIdx.x;
    int e0 = rowstart[i], e1 = rowstart[i + 1];
    float a0 = hs[(size_t)i * 256 + t];  // self loop (already * dinv[i])
    float a1 = 0.f, a2 = 0.f, a3 = 0.f;
    int e = e0;
    for (; e + 4 <= e1; e += 4) {
        int s0 = csr_src[e + 0];
        int s1 = csr_src[e + 1];
        int s2 = csr_src[e + 2];
        int s3 = csr_src[e + 3];
        a0 += hs[(size_t)s0 * 256 + t];
        a1 += hs[(size_t)s1 * 256 + t];
        a2 += hs[(size_t)s2 * 256 + t];
        a3 += hs[(size_t)s3 * 256 + t];
    }
    for (; e < e1; ++e) a0 += hs[(size_t)csr_src[e] * 256 + t];
    float acc = (a0 + a1) + (a2 + a3);
    float v = dinv[i] * acc + bias[t];
    if (do_relu) v = fmaxf(v, 0.f);
    out[(size_t)i * 256 + t] = v;
}

__global__ __launch_bounds__(256) void pool_kernel(const float* __restrict__ h,
                                                   const int* __restrict__ gstart,
                                                   float* __restrict__ pooled) {
    int g = blockIdx.x;
    int t = threadIdx.x;
    int i0 = gstart[g], i1 = gstart[g + 1];
    float m0 = -INFINITY, m1 = -INFINITY, m2 = -INFINITY, m3 = -INFINITY;
    int i = i0;
    for (; i + 4 <= i1; i += 4) {
        m0 = fmaxf(m0, h[(size_t)(i + 0) * 256 + t]);
        m1 = fmaxf(m1, h[(size_t)(i + 1) * 256 + t]);
        m2 = fmaxf(m2, h[(size_t)(i + 2) * 256 + t]);
        m3 = fmaxf(m3, h[(size_t)(i + 3) * 256 + t]);
    }
    for (; i < i1; ++i) m0 = fmaxf(m0, h[(size_t)i * 256 + t]);
    pooled[(size_t)g * 256 + t] = fmaxf(fmaxf(m0, m1), fmaxf(m2, m3));
}

__global__ __launch_bounds__(256) void lsm_kernel(const float* __restrict__ pooled,
                                                  float* __restrict__ out) {
    __shared__ float red[256];
    int g = blockIdx.x, t = threadIdx.x;
    float v = pooled[(size_t)g * 256 + t];
    red[t] = v;
    __syncthreads();
#pragma unroll
    for (int off = 128; off > 0; off >>= 1) {
        if (t < off) red[t] = fmaxf(red[t], red[t + off]);
        __syncthreads();
    }
    float m = red[0];
    __syncthreads();
    red[t] = expf(v - m);
    __syncthreads();
#pragma unroll
    for (int off = 128; off > 0; off >>= 1) {
        if (t < off) red[t] += red[t + off];
        __syncthreads();
    }
    float s = red[0];
    out[(size_t)g * 256 + t] = v - m - logf(s);
}

extern "C" void kernel_launch(void* const* d_in, const int* in_sizes, int n_in,
                              void* d_out, int out_size, void* d_ws, size_t ws_size,
                              hipStream_t stream) {
    const float* x  = (const float*)d_in[0];
    const float* W1 = (const float*)d_in[1];
    const float* b1 = (const float*)d_in[2];
    const float* W2 = (const float*)d_in[3];
    const float* b2 = (const float*)d_in[4];
    const int* edge_index = (const int*)d_in[5];
    const int* batch = (const int*)d_in[6];
    float* out = (float*)d_out;

    const int N = in_sizes[6];
    const int E = in_sizes[5] / 2;
    const int H = in_sizes[2];        // 256
    const int G = out_size / H;       // 512
    const int* src = edge_index;
    const int* dst = edge_index + E;

    // workspace layout
    char* p = (char*)d_ws;
    auto alloc = [&](size_t bytes) {
        char* r = p;
        p += (bytes + 255) & ~(size_t)255;
        return r;
    };
    int*   indeg    = (int*)alloc((size_t)N * 4);
    int*   rowstart = (int*)alloc((size_t)(N + 1) * 4);
    int*   fill     = (int*)alloc((size_t)N * 4);
    int*   bsum     = (int*)alloc(256 * 4);
    float* dinv     = (float*)alloc((size_t)N * 4);
    int*   gstart   = (int*)alloc((size_t)(G + 1) * 4);
    int*   csr_src  = (int*)alloc((size_t)E * 4);
    float* bufA     = (float*)alloc((size_t)N * H * 4);
    float* bufB     = (float*)alloc((size_t)N * H * 4);
    float* pooled   = (float*)alloc((size_t)G * H * 4);

    hipMemsetAsync(indeg, 0, (size_t)N * 4, stream);
    hipMemsetAsync(fill, 0, (size_t)N * 4, stream);

    const int eb = (E + 255) / 256;
    const int nb = (N + 255) / 256;

    count_kernel<<<eb, 256, 0, stream>>>(dst, indeg, E);
    scanA<<<nb, 256, 0, stream>>>(indeg, rowstart, bsum, N);
    scanB<<<1, 256, 0, stream>>>(bsum, nb);
    scanC<<<nb, 256, 0, stream>>>(rowstart, bsum, N, E);
    dinv_kernel<<<nb, 256, 0, stream>>>(indeg, dinv, N);
    fill_csr<<<eb, 256, 0, stream>>>(src, dst, rowstart, fill, csr_src, E);
    gstart_kernel<<<(G + 1 + 255) / 256, 256, 0, stream>>>(batch, gstart, N, G);

    // layer 1: hs = (x @ W1) * dinv[row]; out1 = relu(dinv*(gather+self)+b1)
    gemm_scaled<128><<<(N + 31) / 32, 256, 0, stream>>>(x, W1, dinv, bufA, N);
    agg_kernel<<<N, 256, 0, stream>>>(bufA, rowstart, csr_src, dinv, b1, bufB, 1);
    // layer 2
    gemm_scaled<256><<<(N + 31) / 32, 256, 0, stream>>>(bufB, W2, dinv, bufA, N);
    agg_kernel<<<N, 256, 0, stream>>>(bufA, rowstart, csr_src, dinv, b2, bufB, 0);
    // pooling + log_softmax
    pool_kernel<<<G, 256, 0, stream>>>(bufB, gstart, pooled);
    lsm_kernel<<<G, 256, 0, stream>>>(pooled, out);
}

// Round 4
// 492.082 us; speedup vs baseline: 1.2355x; 1.2355x over previous
//
#include <hip/hip_runtime.h>
#include <hip/hip_bf16.h>

// ---------------------------------------------------------------------------
// GCN forward: 2x GCNConv (MFMA bf16x3 GEMM + CSR gather aggregation)
//              + segment_max + log_softmax
// ---------------------------------------------------------------------------

typedef __attribute__((ext_vector_type(4))) float f32x4;
typedef __attribute__((ext_vector_type(8))) short s16x8;

__device__ inline unsigned short f32_to_bf16_rn(float x) {
    unsigned u = __builtin_bit_cast(unsigned, x);
    unsigned r = u + 0x7FFFu + ((u >> 16) & 1u);
    return (unsigned short)(r >> 16);
}
__device__ inline float bf16_to_f32(unsigned short h) {
    unsigned u = ((unsigned)h) << 16;
    return __builtin_bit_cast(float, u);
}

// ---------------- CSR build ----------------

__global__ __launch_bounds__(256) void count_kernel(const int* __restrict__ dst,
                                                    int* __restrict__ indeg, int E) {
    int e = blockIdx.x * 256 + threadIdx.x;
    if (e < E) atomicAdd(&indeg[dst[e]], 1);
}

__global__ __launch_bounds__(256) void scanA(const int* __restrict__ in,
                                             int* __restrict__ out,
                                             int* __restrict__ bsum, int N) {
    __shared__ int tmp[256];
    int t = threadIdx.x;
    int g = blockIdx.x * 256 + t;
    int v = (g < N) ? in[g] : 0;
    tmp[t] = v;
    __syncthreads();
#pragma unroll
    for (int off = 1; off < 256; off <<= 1) {
        int add = (t >= off) ? tmp[t - off] : 0;
        __syncthreads();
        if (t >= off) tmp[t] += add;
        __syncthreads();
    }
    if (g < N) out[g] = tmp[t] - v;   // exclusive within block
    if (t == 255) bsum[blockIdx.x] = tmp[255];
}

__global__ __launch_bounds__(256) void scanB(int* __restrict__ bsum, int nb) {
    __shared__ int tmp[256];
    int t = threadIdx.x;
    int v = (t < nb) ? bsum[t] : 0;
    tmp[t] = v;
    __syncthreads();
#pragma unroll
    for (int off = 1; off < 256; off <<= 1) {
        int add = (t >= off) ? tmp[t - off] : 0;
        __syncthreads();
        if (t >= off) tmp[t] += add;
        __syncthreads();
    }
    if (t < nb) bsum[t] = tmp[t] - v;  // exclusive
}

__global__ __launch_bounds__(256) void scanC(int* __restrict__ rowstart,
                                             const int* __restrict__ bsum,
                                             int N, int E) {
    int g = blockIdx.x * 256 + threadIdx.x;
    if (g < N) rowstart[g] += bsum[blockIdx.x];
    if (g == 0) rowstart[N] = E;
}

__global__ __launch_bounds__(256) void dinv_kernel(const int* __restrict__ indeg,
                                                   float* __restrict__ dinv, int N) {
    int i = blockIdx.x * 256 + threadIdx.x;
    if (i < N) dinv[i] = rsqrtf((float)(indeg[i] + 1));  // +1 self loop
}

__global__ __launch_bounds__(256) void fill_csr(const int* __restrict__ src,
                                                const int* __restrict__ dst,
                                                const int* __restrict__ rowstart,
                                                int* __restrict__ fill,
                                                int* __restrict__ csr_src, int E) {
    int e = blockIdx.x * 256 + threadIdx.x;
    if (e < E) {
        int d = dst[e];
        int p = rowstart[d] + atomicAdd(&fill[d], 1);
        csr_src[p] = src[e];
    }
}

__global__ __launch_bounds__(256) void gstart_kernel(const int* __restrict__ batch,
                                                     int* __restrict__ gstart,
                                                     int N, int G) {
    int g = blockIdx.x * 256 + threadIdx.x;
    if (g > G) return;
    if (g == G) { gstart[G] = N; return; }
    int lo = 0, hi = N;
    while (lo < hi) {
        int mid = (lo + hi) >> 1;
        if (batch[mid] < g) lo = mid + 1; else hi = mid;
    }
    gstart[g] = lo;
}

// ---------------- weight pre-split: W[K][256] f32 -> packed bf16 hi/lo ------
// Wh/Wl layout: [K/32][256][32]  (k-tile, col, k-within) so GEMM B-staging is
// a coalesced linear copy per k-tile.
__global__ __launch_bounds__(256) void conv_w(const float* __restrict__ W,
                                              unsigned short* __restrict__ Wh,
                                              unsigned short* __restrict__ Wl,
                                              int K) {
    int idx = blockIdx.x * 256 + threadIdx.x;  // over K*256
    if (idx >= K * 256) return;
    int k = idx >> 8, c = idx & 255;
    float w = W[idx];
    unsigned short h = f32_to_bf16_rn(w);
    float lo = w - bf16_to_f32(h);
    unsigned short l = f32_to_bf16_rn(lo);
    size_t o = ((size_t)(k >> 5) * 256 + c) * 32 + (k & 31);
    Wh[o] = h;
    Wl[o] = l;
}

// ---------------- MFMA GEMM: out[row] = (A[row] @ W) * scale[row] -----------
// A:[M,K] f32, W pre-split bf16 hi/lo packed [K/32][256][32], out:[M,256] f32.
// bf16x3: (ah+al)(bh+bl) ~= ah*bh + al*bh + ah*bl  (residual ~2^-16 rel).
// Block: 64 rows x 256 cols, 4 waves; wave w owns cols [w*64, w*64+64).
// C/D map (verified m89/m91): col=lane&15, row=(lane>>4)*4+reg.
// A/B k-chunk permutation is self-cancelling (same bijection on both sides).
template <int K>
__global__ __launch_bounds__(256, 3) void gemm_mfma(const float* __restrict__ A,
                                                    const unsigned short* __restrict__ Bh,
                                                    const unsigned short* __restrict__ Bl,
                                                    const float* __restrict__ scale,
                                                    float* __restrict__ out, int M) {
    constexpr int LDT = 40;  // padded row (bf16 elems): 80 B -> ~2-way banks
    __shared__ __align__(16) unsigned short Ah[64 * LDT];
    __shared__ __align__(16) unsigned short Al[64 * LDT];
    __shared__ __align__(16) unsigned short BhT[256 * LDT];
    __shared__ __align__(16) unsigned short BlT[256 * LDT];

    const int tid  = threadIdx.x;
    const int lane = tid & 63;
    const int w    = tid >> 6;
    const int row0 = blockIdx.x * 64;
    const int q    = lane >> 4;
    const int r16  = lane & 15;

    f32x4 acc[4][4] = {};

    for (int k0 = 0; k0 < K; k0 += 32) {
        // ---- stage A tile (64 x 32 f32 -> hi/lo bf16) ----
        {
            int r = tid >> 2;
            int kq = (tid & 3) * 8;
            int grow = row0 + r;
            float4 v0 = make_float4(0.f, 0.f, 0.f, 0.f);
            float4 v1 = make_float4(0.f, 0.f, 0.f, 0.f);
            if (grow < M) {
                const float* ap = &A[(size_t)grow * K + k0 + kq];
                v0 = *reinterpret_cast<const float4*>(ap);
                v1 = *reinterpret_cast<const float4*>(ap + 4);
            }
            float xs[8] = {v0.x, v0.y, v0.z, v0.w, v1.x, v1.y, v1.z, v1.w};
            s16x8 hv, lv;
#pragma unroll
            for (int j = 0; j < 8; ++j) {
                unsigned short h = f32_to_bf16_rn(xs[j]);
                hv[j] = (short)h;
                lv[j] = (short)f32_to_bf16_rn(xs[j] - bf16_to_f32(h));
            }
            *reinterpret_cast<s16x8*>(&Ah[r * LDT + kq]) = hv;
            *reinterpret_cast<s16x8*>(&Al[r * LDT + kq]) = lv;
        }
        // ---- stage B tile (copy packed 256 x 32 bf16 hi/lo, coalesced) ----
        {
            size_t o = ((size_t)(k0 >> 5) * 256 + tid) * 32;
            const s16x8* bsh = reinterpret_cast<const s16x8*>(Bh + o);
            const s16x8* bsl = reinterpret_cast<const s16x8*>(Bl + o);
#pragma unroll
            for (int j = 0; j < 4; ++j) {
                *reinterpret_cast<s16x8*>(&BhT[tid * LDT + j * 8]) = bsh[j];
                *reinterpret_cast<s16x8*>(&BlT[tid * LDT + j * 8]) = bsl[j];
            }
        }
        __syncthreads();

        // ---- compute ----
        s16x8 bh[4], bl[4];
#pragma unroll
        for (int ct = 0; ct < 4; ++ct) {
            int col = w * 64 + ct * 16 + r16;
            bh[ct] = *reinterpret_cast<const s16x8*>(&BhT[col * LDT + q * 8]);
            bl[ct] = *reinterpret_cast<const s16x8*>(&BlT[col * LDT + q * 8]);
        }
#pragma unroll
        for (int rt = 0; rt < 4; ++rt) {
            int rr = rt * 16 + r16;
            s16x8 ah = *reinterpret_cast<const s16x8*>(&Ah[rr * LDT + q * 8]);
            s16x8 al = *reinterpret_cast<const s16x8*>(&Al[rr * LDT + q * 8]);
#pragma unroll
            for (int ct = 0; ct < 4; ++ct) {
                acc[rt][ct] = __builtin_amdgcn_mfma_f32_16x16x32_bf16(ah, bh[ct], acc[rt][ct], 0, 0, 0);
                acc[rt][ct] = __builtin_amdgcn_mfma_f32_16x16x32_bf16(al, bh[ct], acc[rt][ct], 0, 0, 0);
                acc[rt][ct] = __builtin_amdgcn_mfma_f32_16x16x32_bf16(ah, bl[ct], acc[rt][ct], 0, 0, 0);
            }
        }
        __syncthreads();
    }

    // ---- epilogue: scale by dinv[row], store f32 ----
#pragma unroll
    for (int rt = 0; rt < 4; ++rt) {
#pragma unroll
        for (int i = 0; i < 4; ++i) {
            int grow = row0 + rt * 16 + q * 4 + i;
            if (grow < M) {
                float s = scale[grow];
#pragma unroll
                for (int ct = 0; ct < 4; ++ct) {
                    out[(size_t)grow * 256 + w * 64 + ct * 16 + r16] = acc[rt][ct][i] * s;
                }
            }
        }
    }
}

// out[i] = maybe_relu(dinv[i] * (hs[i] + sum_{e: s->i} hs[s]) + bias)
// 4-way unrolled edge loop keeps 4 row-gathers in flight (avg degree ~16).
__global__ __launch_bounds__(256) void agg_kernel(const float* __restrict__ hs,
                                                  const int* __restrict__ rowstart,
                                                  const int* __restrict__ csr_src,
                                                  const float* __restrict__ dinv,
                                                  const float* __restrict__ bias,
                                                  float* __restrict__ out,
                                                  int do_relu) {
    int i = blockIdx.x;
    int t = threadIdx.x;
    int e0 = rowstart[i], e1 = rowstart[i + 1];
    float a0 = hs[(size_t)i * 256 + t];  // self loop (already * dinv[i])
    float a1 = 0.f, a2 = 0.f, a3 = 0.f;
    int e = e0;
    for (; e + 4 <= e1; e += 4) {
        int s0 = csr_src[e + 0];
        int s1 = csr_src[e + 1];
        int s2 = csr_src[e + 2];
        int s3 = csr_src[e + 3];
        a0 += hs[(size_t)s0 * 256 + t];
        a1 += hs[(size_t)s1 * 256 + t];
        a2 += hs[(size_t)s2 * 256 + t];
        a3 += hs[(size_t)s3 * 256 + t];
    }
    for (; e < e1; ++e) a0 += hs[(size_t)csr_src[e] * 256 + t];
    float acc = (a0 + a1) + (a2 + a3);
    float v = dinv[i] * acc + bias[t];
    if (do_relu) v = fmaxf(v, 0.f);
    out[(size_t)i * 256 + t] = v;
}

__global__ __launch_bounds__(256) void pool_kernel(const float* __restrict__ h,
                                                   const int* __restrict__ gstart,
                                                   float* __restrict__ pooled) {
    int g = blockIdx.x;
    int t = threadIdx.x;
    int i0 = gstart[g], i1 = gstart[g + 1];
    float m0 = -INFINITY, m1 = -INFINITY, m2 = -INFINITY, m3 = -INFINITY;
    int i = i0;
    for (; i + 4 <= i1; i += 4) {
        m0 = fmaxf(m0, h[(size_t)(i + 0) * 256 + t]);
        m1 = fmaxf(m1, h[(size_t)(i + 1) * 256 + t]);
        m2 = fmaxf(m2, h[(size_t)(i + 2) * 256 + t]);
        m3 = fmaxf(m3, h[(size_t)(i + 3) * 256 + t]);
    }
    for (; i < i1; ++i) m0 = fmaxf(m0, h[(size_t)i * 256 + t]);
    pooled[(size_t)g * 256 + t] = fmaxf(fmaxf(m0, m1), fmaxf(m2, m3));
}

__global__ __launch_bounds__(256) void lsm_kernel(const float* __restrict__ pooled,
                                                  float* __restrict__ out) {
    __shared__ float red[256];
    int g = blockIdx.x, t = threadIdx.x;
    float v = pooled[(size_t)g * 256 + t];
    red[t] = v;
    __syncthreads();
#pragma unroll
    for (int off = 128; off > 0; off >>= 1) {
        if (t < off) red[t] = fmaxf(red[t], red[t + off]);
        __syncthreads();
    }
    float m = red[0];
    __syncthreads();
    red[t] = expf(v - m);
    __syncthreads();
#pragma unroll
    for (int off = 128; off > 0; off >>= 1) {
        if (t < off) red[t] += red[t + off];
        __syncthreads();
    }
    float s = red[0];
    out[(size_t)g * 256 + t] = v - m - logf(s);
}

extern "C" void kernel_launch(void* const* d_in, const int* in_sizes, int n_in,
                              void* d_out, int out_size, void* d_ws, size_t ws_size,
                              hipStream_t stream) {
    const float* x  = (const float*)d_in[0];
    const float* W1 = (const float*)d_in[1];
    const float* b1 = (const float*)d_in[2];
    const float* W2 = (const float*)d_in[3];
    const float* b2 = (const float*)d_in[4];
    const int* edge_index = (const int*)d_in[5];
    const int* batch = (const int*)d_in[6];
    float* out = (float*)d_out;

    const int N = in_sizes[6];
    const int E = in_sizes[5] / 2;
    const int H = in_sizes[2];        // 256
    const int G = out_size / H;       // 512
    const int K1 = in_sizes[1] / H;   // 128
    const int* src = edge_index;
    const int* dst = edge_index + E;

    // workspace layout
    char* p = (char*)d_ws;
    auto alloc = [&](size_t bytes) {
        char* r = p;
        p += (bytes + 255) & ~(size_t)255;
        return r;
    };
    int*   indeg    = (int*)alloc((size_t)N * 4);
    int*   rowstart = (int*)alloc((size_t)(N + 1) * 4);
    int*   fill     = (int*)alloc((size_t)N * 4);
    int*   bsum     = (int*)alloc(256 * 4);
    float* dinv     = (float*)alloc((size_t)N * 4);
    int*   gstart   = (int*)alloc((size_t)(G + 1) * 4);
    int*   csr_src  = (int*)alloc((size_t)E * 4);
    float* bufA     = (float*)alloc((size_t)N * H * 4);
    float* bufB     = (float*)alloc((size_t)N * H * 4);
    float* pooled   = (float*)alloc((size_t)G * H * 4);
    unsigned short* w1h = (unsigned short*)alloc((size_t)K1 * H * 2);
    unsigned short* w1l = (unsigned short*)alloc((size_t)K1 * H * 2);
    unsigned short* w2h = (unsigned short*)alloc((size_t)H * H * 2);
    unsigned short* w2l = (unsigned short*)alloc((size_t)H * H * 2);

    hipMemsetAsync(indeg, 0, (size_t)N * 4, stream);
    hipMemsetAsync(fill, 0, (size_t)N * 4, stream);

    const int eb = (E + 255) / 256;
    const int nb = (N + 255) / 256;

    count_kernel<<<eb, 256, 0, stream>>>(dst, indeg, E);
    scanA<<<nb, 256, 0, stream>>>(indeg, rowstart, bsum, N);
    scanB<<<1, 256, 0, stream>>>(bsum, nb);
    scanC<<<nb, 256, 0, stream>>>(rowstart, bsum, N, E);
    dinv_kernel<<<nb, 256, 0, stream>>>(indeg, dinv, N);
    fill_csr<<<eb, 256, 0, stream>>>(src, dst, rowstart, fill, csr_src, E);
    gstart_kernel<<<(G + 1 + 255) / 256, 256, 0, stream>>>(batch, gstart, N, G);
    conv_w<<<(K1 * H + 255) / 256, 256, 0, stream>>>(W1, w1h, w1l, K1);
    conv_w<<<(H * H + 255) / 256, 256, 0, stream>>>(W2, w2h, w2l, H);

    const int gb = (N + 63) / 64;
    // layer 1: hs = (x @ W1) * dinv[row]; out1 = relu(dinv*(gather+self)+b1)
    gemm_mfma<128><<<gb, 256, 0, stream>>>(x, w1h, w1l, dinv, bufA, N);
    agg_kernel<<<N, 256, 0, stream>>>(bufA, rowstart, csr_src, dinv, b1, bufB, 1);
    // layer 2
    gemm_mfma<256><<<gb, 256, 0, stream>>>(bufB, w2h, w2l, dinv, bufA, N);
    agg_kernel<<<N, 256, 0, stream>>>(bufA, rowstart, csr_src, dinv, b2, bufB, 0);
    // pooling + log_softmax
    pool_kernel<<<G, 256, 0, stream>>>(bufB, gstart, pooled);
    lsm_kernel<<<G, 256, 0, stream>>>(pooled, out);
}